// Round 1
// baseline (869.866 us; speedup 1.0000x reference)
//
#include <hip/hip_runtime.h>

#define NEG_INF (-1e30f)

constexpr int T = 1024;
constexpr int B = 64;
constexpr int V = 512;
constexpr int L = 256;
constexpr int S = 2 * L + 1;   // 513
constexpr int NT = 256;        // threads per block in recursion kernel

// ---------------------------------------------------------------------------
// Kernel 1: lse[t*B+b] = log(sum_v exp(acts[t,b,v])).  One wave per row.
// acts ~ N(0,1) so direct exp-sum is numerically safe in fp32 (max ~ e^5.5).
// ---------------------------------------------------------------------------
__global__ __launch_bounds__(256) void lse_kernel(const float* __restrict__ acts,
                                                  float* __restrict__ lse) {
    int gid  = blockIdx.x * blockDim.x + threadIdx.x;
    int row  = gid >> 6;
    int lane = gid & 63;
    if (row >= T * B) return;
    const float* p = acts + (size_t)row * V;
    float4 x0 = ((const float4*)p)[lane];        // elems 4*lane   .. 4*lane+3
    float4 x1 = ((const float4*)p)[lane + 64];   // elems 256+4*lane ..
    float s = __expf(x0.x) + __expf(x0.y) + __expf(x0.z) + __expf(x0.w)
            + __expf(x1.x) + __expf(x1.y) + __expf(x1.z) + __expf(x1.w);
#pragma unroll
    for (int off = 32; off > 0; off >>= 1) s += __shfl_down(s, off, 64);
    if (lane == 0) lse[row] = __logf(s);
}

// ---------------------------------------------------------------------------
// Kernel 2: serial alpha recursion. One block per batch, 256 threads.
// Thread tid owns states {tid, tid+256, tid+512 (tid==0 only)}.
// Alpha double-buffered in LDS (+2 front pad = NEG_INF so s-1/s-2 reads are
// branch-free). One barrier per time step. Gathers for step t+1 prefetched
// during step t (they don't depend on alpha).
// ---------------------------------------------------------------------------
__global__ __launch_bounds__(NT) void ctc_alpha_kernel(
    const float* __restrict__ acts,
    const int* __restrict__ labels,
    const int* __restrict__ act_lens,
    const int* __restrict__ label_lens,
    const float* __restrict__ lse,
    float* __restrict__ out)
{
    __shared__ int   ext_sh[S];
    __shared__ int   allow_sh[S];
    __shared__ float alpha[2][S + 2];

    const int b   = blockIdx.x;
    const int tid = threadIdx.x;
    const int lab_len = label_lens[b];
    const int a_len   = act_lens[b];

    // offsets = exclusive cumsum of label_lens (tiny, cached reads)
    int offset = 0;
    for (int i = 0; i < b; ++i) offset += label_lens[i];

    // ext: blanks at even s, labels at odd s (0-padded past lab_len)
    for (int s = tid; s < S; s += NT) {
        int e = 0;
        if (s & 1) {
            int j = s >> 1;
            if (j < lab_len) {
                int g = offset + j;
                g = g < (B * L - 1) ? g : (B * L - 1);
                e = labels[g];
            }
        }
        ext_sh[s] = e;
    }
    __syncthreads();
    for (int s = tid; s < S; s += NT) {
        allow_sh[s] = (s >= 2) && (ext_sh[s] != 0) && (ext_sh[s] != ext_sh[s - 2]);
    }
    if (tid < 2) { alpha[0][tid] = NEG_INF; alpha[1][tid] = NEG_INF; }
    for (int s = tid; s < S; s += NT) alpha[0][s + 2] = NEG_INF;
    __syncthreads();

    if (tid == 0) {
        float l0 = lse[b];                 // t = 0
        const float* row0 = acts + (size_t)b * V;
        alpha[0][0 + 2] = row0[ext_sh[0]] - l0;
        alpha[0][1 + 2] = row0[ext_sh[1]] - l0;
    }
    __syncthreads();

    const int  s0 = tid, s1 = tid + NT, s2 = tid + 2 * NT;
    const bool has2 = (s2 < S);            // only tid == 0
    const int  e0 = ext_sh[s0], e1 = ext_sh[s1];
    const int  e2 = has2 ? ext_sh[s2] : 0;
    const int  al0 = allow_sh[s0], al1 = allow_sh[s1];
    const int  al2 = has2 ? allow_sh[s2] : 0;

    const float* actb = acts + (size_t)b * V;
    const size_t rstride = (size_t)B * V;

    // preload t = 1
    float v0 = actb[rstride + e0];
    float v1 = actb[rstride + e1];
    float v2 = has2 ? actb[rstride + e2] : 0.f;
    float lcur = lse[B + b];

    int cur = 0;
    for (int t = 1; t < T; ++t) {
        // prefetch t+1 (independent of alpha)
        float nv0 = 0.f, nv1 = 0.f, nv2 = 0.f, nls = 0.f;
        if (t + 1 < T) {
            const float* rn = actb + rstride * (size_t)(t + 1);
            nv0 = rn[e0];
            nv1 = rn[e1];
            if (has2) nv2 = rn[e2];
            nls = lse[(t + 1) * B + b];
        }

        const float* ao = &alpha[cur][2];
        float*       an = &alpha[cur ^ 1][2];
        const bool   upd = (t < a_len);

        {
            float A1 = ao[s0], A2 = ao[s0 - 1];
            float A3 = al0 ? ao[s0 - 2] : NEG_INF;
            float m = fmaxf(A1, fmaxf(A2, A3));
            float r = m + __logf(__expf(A1 - m) + __expf(A2 - m) + __expf(A3 - m));
            an[s0] = upd ? (v0 - lcur + r) : A1;
        }
        {
            float A1 = ao[s1], A2 = ao[s1 - 1];
            float A3 = al1 ? ao[s1 - 2] : NEG_INF;
            float m = fmaxf(A1, fmaxf(A2, A3));
            float r = m + __logf(__expf(A1 - m) + __expf(A2 - m) + __expf(A3 - m));
            an[s1] = upd ? (v1 - lcur + r) : A1;
        }
        if (has2) {
            float A1 = ao[s2], A2 = ao[s2 - 1];
            float A3 = al2 ? ao[s2 - 2] : NEG_INF;
            float m = fmaxf(A1, fmaxf(A2, A3));
            float r = m + __logf(__expf(A1 - m) + __expf(A2 - m) + __expf(A3 - m));
            an[s2] = upd ? (v2 - lcur + r) : A1;
        }
        __syncthreads();
        v0 = nv0; v1 = nv1; v2 = nv2; lcur = nls;
        cur ^= 1;
    }

    if (tid == 0) {
        const float* af = &alpha[cur][2];
        int send = 2 * lab_len;
        float ae  = af[send];
        int   si2 = (send - 1 > 0) ? send - 1 : 0;
        float ae2 = af[si2];
        float m = fmaxf(ae, ae2);
        float loss = -(m + __logf(__expf(ae - m) + __expf(ae2 - m)));
        atomicAdd(out, loss);
    }
}

extern "C" void kernel_launch(void* const* d_in, const int* in_sizes, int n_in,
                              void* d_out, int out_size, void* d_ws, size_t ws_size,
                              hipStream_t stream) {
    const float* acts       = (const float*)d_in[0];
    const int*   labels     = (const int*)d_in[1];
    const int*   act_lens   = (const int*)d_in[2];
    const int*   label_lens = (const int*)d_in[3];
    float*       out        = (float*)d_out;
    float*       lse        = (float*)d_ws;   // T*B floats = 256 KB

    hipMemsetAsync(d_out, 0, sizeof(float), stream);

    const int rows = T * B;                    // 65536 waves, 4 waves/block
    lse_kernel<<<(rows * 64 + 255) / 256, 256, 0, stream>>>(acts, lse);
    ctc_alpha_kernel<<<B, NT, 0, stream>>>(acts, labels, act_lens, label_lens, lse, out);
}

// Round 2
// 729.280 us; speedup vs baseline: 1.1928x; 1.1928x over previous
//
#include <hip/hip_runtime.h>

constexpr int T = 1024;
constexpr int B = 64;
constexpr int V = 512;
constexpr int L = 256;
constexpr int S = 2 * L + 1;   // 513

// ---------------------------------------------------------------------------
// Kernel 1: per-row logsumexp, summed per batch: sum_lse[b] += lse(acts[t,b,:])
// One wave per row. acts ~ N(0,1) so direct exp-sum is fp32-safe.
// ---------------------------------------------------------------------------
__global__ __launch_bounds__(256) void lse_kernel(const float* __restrict__ acts,
                                                  const int* __restrict__ act_lens,
                                                  float* __restrict__ sum_lse) {
    int gid  = blockIdx.x * blockDim.x + threadIdx.x;
    int row  = gid >> 6;
    int lane = gid & 63;
    if (row >= T * B) return;
    const float* p = acts + (size_t)row * V;
    float4 x0 = ((const float4*)p)[lane];
    float4 x1 = ((const float4*)p)[lane + 64];
    float s = __expf(x0.x) + __expf(x0.y) + __expf(x0.z) + __expf(x0.w)
            + __expf(x1.x) + __expf(x1.y) + __expf(x1.z) + __expf(x1.w);
#pragma unroll
    for (int off = 32; off; off >>= 1) s += __shfl_xor(s, off, 64);
    int t = row >> 6;          // row = t*B + b, B = 64
    int b = row & 63;
    if (lane == 0 && t < act_lens[b]) atomicAdd(&sum_lse[b], __logf(s));
}

// ---------------------------------------------------------------------------
// Kernel 2: linear-space alpha recursion. ONE WAVE per batch — no barriers in
// the T loop, so an 8-row-deep register prefetch pipeline stays in flight
// (the __syncthreads vmcnt(0) drain of R1 is gone). Lane l owns states
// [8l, 8l+8); lane 63 also owns state 512. Cross-lane dep = one shfl_up.
// Even states are blanks (shared broadcast logit); odd states gather their
// label's logit. Max-rescale every 8 steps keeps fp32 in range; softmax
// denominators are factored out and subtracted once via sum_lse.
// ---------------------------------------------------------------------------
__global__ __launch_bounds__(64) void ctc_lin_kernel(
    const float* __restrict__ acts,
    const int* __restrict__ labels,
    const int* __restrict__ act_lens,
    const int* __restrict__ label_lens,
    const float* __restrict__ sum_lse,
    float* __restrict__ out)
{
    const int b    = blockIdx.x;
    const int lane = threadIdx.x;
    const int lab_len = label_lens[b];
    const int a_len   = act_lens[b];

    int offset = 0;
    for (int i = 0; i < b; ++i) offset += label_lens[i];

    // This lane's 4 odd-state labels (label idx 4*lane + i), plus the label
    // just before (for the repeated-label skip test of state 8l+1).
    int e[4]; float allowf[4];
    int eprev;
    {
        int li = 4 * lane - 1;
        eprev = (li >= 0 && li < lab_len) ? labels[min(offset + li, B * L - 1)] : 0;
    }
#pragma unroll
    for (int i = 0; i < 4; ++i) {
        int li = 4 * lane + i;
        e[i] = (li < lab_len) ? labels[min(offset + li, B * L - 1)] : 0;
    }
#pragma unroll
    for (int i = 0; i < 4; ++i) {
        int s  = 8 * lane + 2 * i + 1;
        int ep = (i == 0) ? eprev : e[i - 1];
        allowf[i] = (s >= 2 && e[i] != 0 && e[i] != ep) ? 1.f : 0.f;
    }

    const float* actb = acts + (size_t)b * V;
    const size_t rstride = (size_t)B * V;

    float A[8], A8 = 0.f, acc = 0.f;
#pragma unroll
    for (int j = 0; j < 8; ++j) A[j] = 0.f;
    if (lane == 0) {
        A[0] = __expf(actb[0]);     // state 0: blank
        A[1] = __expf(actb[e[0]]);  // state 1: first label (or blank if L=0)
    }

    // Prefetch pipeline: pf[j] holds row t+j's 4 gathers + blank logit.
    float pf[8][5];
#pragma unroll
    for (int j = 0; j < 8; ++j) {
        const float* rp = actb + rstride * (size_t)(1 + j);
        pf[j][0] = rp[e[0]]; pf[j][1] = rp[e[1]];
        pf[j][2] = rp[e[2]]; pf[j][3] = rp[e[3]];
        pf[j][4] = rp[0];
    }

    auto step = [&](const float (&P)[5]) {
        float ub = __expf(P[4]);
        float u0 = __expf(P[0]);
        float u1 = __expf(P[1]);
        float u2 = __expf(P[2]);
        float u3 = __expf(P[3]);
        float pA7 = __shfl_up(A[7], 1, 64);
        if (lane == 0) pA7 = 0.f;
        // state 512 (lane 63; harmless garbage elsewhere, rescale-safe)
        A8   = ub * (A8 + A[7]);
        // descending order: A[j-1], A[j-2] still hold old values
        A[7] = u3 * fmaf(allowf[3], A[5], A[7] + A[6]);
        A[6] = ub * (A[6] + A[5]);
        A[5] = u2 * fmaf(allowf[2], A[3], A[5] + A[4]);
        A[4] = ub * (A[4] + A[3]);
        A[3] = u1 * fmaf(allowf[1], A[1], A[3] + A[2]);
        A[2] = ub * (A[2] + A[1]);
        A[1] = u0 * fmaf(allowf[0], pA7, A[1] + A[0]);
        A[0] = ub * (A[0] + pA7);
    };

    int t = 1;
    while (t + 8 <= a_len) {
#pragma unroll
        for (int j = 0; j < 8; ++j) {
            step(pf[j]);
            int r = t + j + 8;                 // refill with row t+j+8
            r = r < T ? r : T - 1;             // clamp: unconditional issue
            const float* rp = actb + rstride * (size_t)r;
            pf[j][0] = rp[e[0]]; pf[j][1] = rp[e[1]];
            pf[j][2] = rp[e[2]]; pf[j][3] = rp[e[3]];
            pf[j][4] = rp[0];
        }
        // rescale: keep max(A) ~ 1 (growth <= ~735^8 per chunk, fp32-safe)
        float m = fmaxf(A8, A[0]);
#pragma unroll
        for (int j = 1; j < 8; ++j) m = fmaxf(m, A[j]);
#pragma unroll
        for (int off = 32; off; off >>= 1) m = fmaxf(m, __shfl_xor(m, off, 64));
        m = fmaxf(m, 1e-30f);
        float inv = __builtin_amdgcn_rcpf(m);
        acc += __logf(m);
        A8 *= inv;
#pragma unroll
        for (int j = 0; j < 8; ++j) A[j] *= inv;
        t += 8;
    }
    // tail: <8 steps, pf[i] = row t+i (invariant holds from refills/preload)
#pragma unroll
    for (int i = 0; i < 8; ++i) {
        if (t + i < a_len) step(pf[i]);
    }

    // epilogue: pick out alpha[2*lab_len], alpha[2*lab_len-1]
    __shared__ float sA[S];
#pragma unroll
    for (int j = 0; j < 8; ++j) sA[8 * lane + j] = A[j];
    if (lane == 63) sA[512] = A8;
    __syncthreads();
    if (lane == 0) {
        int send = 2 * lab_len;
        int s2i  = send - 1 > 0 ? send - 1 : 0;
        float v  = sA[send] + sA[s2i];          // linear-space logaddexp
        float loss = sum_lse[b] - acc - __logf(v);
        atomicAdd(out, loss);
    }
}

extern "C" void kernel_launch(void* const* d_in, const int* in_sizes, int n_in,
                              void* d_out, int out_size, void* d_ws, size_t ws_size,
                              hipStream_t stream) {
    const float* acts       = (const float*)d_in[0];
    const int*   labels     = (const int*)d_in[1];
    const int*   act_lens   = (const int*)d_in[2];
    const int*   label_lens = (const int*)d_in[3];
    float*       out        = (float*)d_out;
    float*       sum_lse    = (float*)d_ws;    // B floats

    hipMemsetAsync(d_out, 0, sizeof(float), stream);
    hipMemsetAsync(d_ws, 0, B * sizeof(float), stream);

    lse_kernel<<<(T * B * 64) / 256, 256, 0, stream>>>(acts, act_lens, sum_lse);
    ctc_lin_kernel<<<B, 64, 0, stream>>>(acts, labels, act_lens, label_lens,
                                         sum_lse, out);
}

// Round 4
// 332.531 us; speedup vs baseline: 2.6159x; 2.1931x over previous
//
#include <hip/hip_runtime.h>

constexpr int T = 1024;
constexpr int B = 64;
constexpr int V = 512;
constexpr int L = 256;
constexpr int S = 2 * L + 1;   // 513

// ws layout
// [0]        lse_rows : T*B floats (256 KB)
// [256K]     blankB   : T*B floats (256 KB)   (packed path only)
// [1M]       packedL  : T*B*256 floats (64 MB) (packed path only)

// ---------------------------------------------------------------------------
// Setup: one wave per (t,b) row.
//  - lse_rows[r] = log(sum_v exp(acts[r*V+v]))            (always)
//  - packedL[r][j] = acts[r*V + label_j]  (blank-filled past lab_len)
//    blankB[r] = acts[r*V]                                 (PACKED only)
// Row staged in LDS so lanes can gather by label index.
// ---------------------------------------------------------------------------
template<bool PACKED>
__global__ __launch_bounds__(256) void setup_kernel(
    const float* __restrict__ acts, const int* __restrict__ labels,
    const int* __restrict__ label_lens, float* __restrict__ lse_rows,
    float* __restrict__ packedL, float* __restrict__ blankB)
{
    __shared__ float rows[4][V];
    const int w    = threadIdx.x >> 6;
    const int lane = threadIdx.x & 63;
    const int r    = blockIdx.x * 4 + w;          // r = t*B + b
    const float* p = acts + (size_t)r * V;

    float4 x0 = ((const float4*)p)[lane];
    float4 x1 = ((const float4*)p)[lane + 64];
    float s = __expf(x0.x) + __expf(x0.y) + __expf(x0.z) + __expf(x0.w)
            + __expf(x1.x) + __expf(x1.y) + __expf(x1.z) + __expf(x1.w);
#pragma unroll
    for (int off = 32; off; off >>= 1) s += __shfl_xor(s, off, 64);
    if (lane == 0) lse_rows[r] = __logf(s);

    if constexpr (PACKED) {
        ((float4*)rows[w])[lane]      = x0;
        ((float4*)rows[w])[lane + 64] = x1;
        const int b = r & (B - 1);
        const int lab_len = label_lens[b];
        int off = 0;
        for (int i = 0; i < b; ++i) off += label_lens[i];
        __syncthreads();
        const float blank = rows[w][0];
        float g[4];
#pragma unroll
        for (int i = 0; i < 4; ++i) {
            int j = 4 * lane + i;
            g[i] = (j < lab_len) ? rows[w][labels[min(off + j, B * L - 1)]]
                                 : blank;
        }
        float4 gv = {g[0], g[1], g[2], g[3]};
        ((float4*)(packedL + (size_t)r * 256))[lane] = gv;
        if (lane == 0) blankB[r] = blank;
    }
}

// ---------------------------------------------------------------------------
// Row fetch for the scan: packed = 1 coalesced float4 + 1 broadcast dword.
// ---------------------------------------------------------------------------
template<bool PACKED>
__device__ __forceinline__ void load_row(const float* __restrict__ acts,
                                         const float* __restrict__ packedL,
                                         const float* __restrict__ blankB,
                                         int r, int lane, const int e[4],
                                         float P[5])
{
    if constexpr (PACKED) {
        float4 g = ((const float4*)(packedL + (size_t)r * 256))[lane];
        P[0] = g.x; P[1] = g.y; P[2] = g.z; P[3] = g.w;
        P[4] = blankB[r];
    } else {
        const float* rp = acts + (size_t)r * V;
        P[0] = rp[e[0]]; P[1] = rp[e[1]]; P[2] = rp[e[2]]; P[3] = rp[e[3]];
        P[4] = rp[0];
    }
}

// ---------------------------------------------------------------------------
// Fwd/bwd linear-space CTC scan. Block b: wave0 = alpha forward t=1..th,
// wave1 = beta backward t=a_len-2..th+1 (+ bracket W). No barriers inside the
// serial loops; one __syncthreads at the join. Lane l owns states 8l..8l+7
// (+ state 512 on lane 63). 8-row register prefetch pipeline; max-rescale
// every 8 steps. Junction done in LOG space: linear dot of the two
// independently-rescaled sides flushes to 0 in fp32 (gfx950 flushes f32
// denorms; entropy spread across states is ~300 nats) — that was R3's inf.
// ---------------------------------------------------------------------------
template<bool PACKED>
__global__ __launch_bounds__(128) void ctc_kernel(
    const float* __restrict__ acts, const int* __restrict__ labels,
    const int* __restrict__ act_lens, const int* __restrict__ label_lens,
    const float* __restrict__ lse_rows, const float* __restrict__ packedL,
    const float* __restrict__ blankB, float* __restrict__ out)
{
    const int b    = blockIdx.x;
    const int wave = threadIdx.x >> 6;
    const int lane = threadIdx.x & 63;
    const int lab_len = label_lens[b];
    const int a_len   = act_lens[b];
    const int th      = (a_len - 1) >> 1;

    int off = 0;
    for (int i = 0; i < b; ++i) off += label_lens[i];

    // labels owned by this lane (label idx 4l..4l+3) + neighbors
    int e[4], eprev, enext;
    {
        int li = 4 * lane - 1;
        eprev = (li >= 0 && li < lab_len) ? labels[min(off + li, B * L - 1)] : 0;
        int ln = 4 * lane + 4;
        enext = (ln < lab_len) ? labels[min(off + ln, B * L - 1)] : 0;
    }
#pragma unroll
    for (int i = 0; i < 4; ++i) {
        int li = 4 * lane + i;
        e[i] = (li < lab_len) ? labels[min(off + li, B * L - 1)] : 0;
    }
    float alF[4], alB[4];
#pragma unroll
    for (int i = 0; i < 4; ++i) {
        int s  = 8 * lane + 2 * i + 1;
        int ep = (i == 0) ? eprev : e[i - 1];
        int en = (i == 3) ? enext : e[i + 1];
        alF[i] = (s >= 2 && e[i] != 0 && e[i] != ep) ? 1.f : 0.f;
        alB[i] = (en != 0 && en != e[i]) ? 1.f : 0.f;
    }

    __shared__ float sbr[S];
    __shared__ float s_accb;

    float A[8], A8 = 0.f, acc = 0.f, sls = 0.f;
#pragma unroll
    for (int j = 0; j < 8; ++j) A[j] = 0.f;
    float pf[8][5];

    auto rescale = [&]() {
        float m = fmaxf(A8, A[0]);
#pragma unroll
        for (int j = 1; j < 8; ++j) m = fmaxf(m, A[j]);
#pragma unroll
        for (int o = 32; o; o >>= 1) m = fmaxf(m, __shfl_xor(m, o, 64));
        m = fmaxf(m, 1e-30f);
        float inv = __builtin_amdgcn_rcpf(m);
        acc += __logf(m);
        A8 *= inv;
#pragma unroll
        for (int j = 0; j < 8; ++j) A[j] *= inv;
    };

    if (wave == 0) {
        // ---- per-batch sum of row-lse (L2-resident) ----
        for (int t = lane; t < a_len; t += 64) sls += lse_rows[t * B + b];
#pragma unroll
        for (int o = 32; o; o >>= 1) sls += __shfl_xor(sls, o, 64);

        // ---- alpha init (t = 0, row r = b) ----
        {
            float P0[5];
            load_row<PACKED>(acts, packedL, blankB, b, lane, e, P0);
            if (lane == 0) {
                A[0] = __expf(P0[4]);
                A[1] = __expf(P0[0]);
            }
        }
        auto stepF = [&](const float (&P)[5]) {
            float ub = __expf(P[4]);
            float u0 = __expf(P[0]), u1 = __expf(P[1]);
            float u2 = __expf(P[2]), u3 = __expf(P[3]);
            float pA7 = __shfl_up(A[7], 1, 64);
            if (lane == 0) pA7 = 0.f;
            A8   = ub * (A8 + A[7]);
            A[7] = u3 * fmaf(alF[3], A[5], A[7] + A[6]);
            A[6] = ub * (A[6] + A[5]);
            A[5] = u2 * fmaf(alF[2], A[3], A[5] + A[4]);
            A[4] = ub * (A[4] + A[3]);
            A[3] = u1 * fmaf(alF[1], A[1], A[3] + A[2]);
            A[2] = ub * (A[2] + A[1]);
            A[1] = u0 * fmaf(alF[0], pA7, A[1] + A[0]);
            A[0] = ub * (A[0] + pA7);
        };
#pragma unroll
        for (int j = 0; j < 8; ++j) {
            int r = min(1 + j, T - 1);
            load_row<PACKED>(acts, packedL, blankB, r * B + b, lane, e, pf[j]);
        }
        int t = 1;
        while (t + 8 <= th + 1) {
#pragma unroll
            for (int j = 0; j < 8; ++j) {
                stepF(pf[j]);
                int r = min(t + j + 8, T - 1);
                load_row<PACKED>(acts, packedL, blankB, r * B + b, lane, e, pf[j]);
            }
            rescale();
            t += 8;
        }
#pragma unroll
        for (int i = 0; i < 8; ++i)
            if (t + i <= th) stepF(pf[i]);
        rescale();
    } else {
        // ---- beta init (t = a_len-1) ----
        const int send = 2 * lab_len;
        {
            int rl = (a_len - 1) * B + b;
            float ubl, ue;
            if constexpr (PACKED) {
                ubl = __expf(blankB[rl]);
                ue  = (lab_len > 0) ? __expf(packedL[(size_t)rl * 256 + (lab_len - 1)]) : 0.f;
            } else {
                const float* rp = acts + (size_t)rl * V;
                ubl = __expf(rp[0]);
                ue  = (lab_len > 0) ? __expf(rp[labels[min(off + lab_len - 1, B * L - 1)]]) : 0.f;
            }
#pragma unroll
            for (int j = 0; j < 8; ++j) {
                int s = 8 * lane + j;
                A[j] = (s == send) ? ubl : ((s == send - 1) ? ue : 0.f);
            }
            A8 = (lane == 63 && send == 512) ? ubl : 0.f;
        }
        auto stepB = [&](const float (&P)[5]) {
            float ub = __expf(P[4]);
            float u0 = __expf(P[0]), u1 = __expf(P[1]);
            float u2 = __expf(P[2]), u3 = __expf(P[3]);
            float nB0 = __shfl_down(A[0], 1, 64);
            float nB1 = __shfl_down(A[1], 1, 64);
            if (lane == 63) { nB0 = A8; nB1 = 0.f; }
            A8   = ub * A8;
            A[0] = ub * (A[0] + A[1]);
            A[1] = u0 * fmaf(alB[0], A[3], A[1] + A[2]);
            A[2] = ub * (A[2] + A[3]);
            A[3] = u1 * fmaf(alB[1], A[5], A[3] + A[4]);
            A[4] = ub * (A[4] + A[5]);
            A[5] = u2 * fmaf(alB[2], A[7], A[5] + A[6]);
            A[6] = ub * (A[6] + A[7]);
            A[7] = u3 * fmaf(alB[3], nB1, A[7] + nB0);
        };
#pragma unroll
        for (int j = 0; j < 8; ++j) {
            int r = max(a_len - 2 - j, 0);
            load_row<PACKED>(acts, packedL, blankB, r * B + b, lane, e, pf[j]);
        }
        int t = a_len - 2;
        while (t - 8 >= th) {
#pragma unroll
            for (int j = 0; j < 8; ++j) {
                stepB(pf[j]);
                int r = max(t - j - 8, 0);
                load_row<PACKED>(acts, packedL, blankB, r * B + b, lane, e, pf[j]);
            }
            rescale();
            t -= 8;
        }
#pragma unroll
        for (int i = 0; i < 8; ++i)
            if (t - i >= th + 1) stepB(pf[i]);
        rescale();
        // ---- bracket W(s) = B(s) + B(s+1) + allowB*B(s+2), B = beta_{th+1} --
        {
            float nB0 = __shfl_down(A[0], 1, 64);
            float nB1 = __shfl_down(A[1], 1, 64);
            if (lane == 63) { nB0 = A8; nB1 = 0.f; }
            float br[8];
            br[0] = A[0] + A[1];
            br[1] = fmaf(alB[0], A[3], A[1] + A[2]);
            br[2] = A[2] + A[3];
            br[3] = fmaf(alB[1], A[5], A[3] + A[4]);
            br[4] = A[4] + A[5];
            br[5] = fmaf(alB[2], A[7], A[5] + A[6]);
            br[6] = A[6] + A[7];
            br[7] = fmaf(alB[3], nB1, A[7] + nB0);
#pragma unroll
            for (int j = 0; j < 8; ++j) sbr[8 * lane + j] = br[j];
            if (lane == 63) sbr[512] = A8;
            if (lane == 0)  s_accb = acc;
        }
    }
    __syncthreads();
    if (wave == 0) {
        // LOG-space junction: p(s) = log alpha(s) + log W(s), guarded logs so
        // dead states give ~-170 (finite), then stable logsumexp over s.
        auto lg = [](float x) { return __logf(fmaxf(x, 1e-37f)); };
        float p[8];
        float pmax = -3.0e38f;
#pragma unroll
        for (int j = 0; j < 8; ++j) {
            p[j] = lg(A[j]) + lg(sbr[8 * lane + j]);
            pmax = fmaxf(pmax, p[j]);
        }
        float p8 = -3.0e38f;
        if (lane == 63) {
            p8 = lg(A8) + lg(sbr[512]);
            pmax = fmaxf(pmax, p8);
        }
#pragma unroll
        for (int o = 32; o; o >>= 1) pmax = fmaxf(pmax, __shfl_xor(pmax, o, 64));
        float dot = 0.f;
#pragma unroll
        for (int j = 0; j < 8; ++j) dot += __expf(p[j] - pmax);
        if (lane == 63) dot += __expf(p8 - pmax);
#pragma unroll
        for (int o = 32; o; o >>= 1) dot += __shfl_xor(dot, o, 64);
        if (lane == 0) {
            float loss = sls - acc - s_accb - (pmax + __logf(dot));
            atomicAdd(out, loss);
        }
    }
}

extern "C" void kernel_launch(void* const* d_in, const int* in_sizes, int n_in,
                              void* d_out, int out_size, void* d_ws, size_t ws_size,
                              hipStream_t stream) {
    const float* acts       = (const float*)d_in[0];
    const int*   labels     = (const int*)d_in[1];
    const int*   act_lens   = (const int*)d_in[2];
    const int*   label_lens = (const int*)d_in[3];
    float*       out        = (float*)d_out;

    float* lse_rows = (float*)d_ws;
    float* blankB   = (float*)((char*)d_ws + (size_t)T * B * 4);
    float* packedL  = (float*)((char*)d_ws + (1u << 20));
    const bool packed = ws_size >= (size_t)(1u << 20) + (size_t)T * B * 256 * 4;

    hipMemsetAsync(d_out, 0, sizeof(float), stream);

    if (packed) {
        setup_kernel<true><<<T * B / 4, 256, 0, stream>>>(
            acts, labels, label_lens, lse_rows, packedL, blankB);
        ctc_kernel<true><<<B, 128, 0, stream>>>(
            acts, labels, act_lens, label_lens, lse_rows, packedL, blankB, out);
    } else {
        setup_kernel<false><<<T * B / 4, 256, 0, stream>>>(
            acts, labels, label_lens, lse_rows, packedL, blankB);
        ctc_kernel<false><<<B, 128, 0, stream>>>(
            acts, labels, act_lens, label_lens, lse_rows, packedL, blankB, out);
    }
}